// Round 1
// baseline (9999.884 us; speedup 1.0000x reference)
//
#include <hip/hip_runtime.h>
#include <math.h>

// Problem dims (fixed)
#define N_ 20000
#define E_ 100000
#define B_ 128
#define F_IN_ 14
#define DIM_ 64
#define E_FEAT_ 4
#define MLP_H_ 128
#define EWC_ 4096   // DIM*DIM

// ---------------------------------------------------------------------------
// lin0: out[n,d] = relu(x[n,:] @ lin0_w + b)
__global__ void lin0_kernel(const float* __restrict__ x, const float* __restrict__ w,
                            const float* __restrict__ b, float* __restrict__ out) {
    int idx = blockIdx.x * blockDim.x + threadIdx.x;
    if (idx >= N_ * DIM_) return;
    int n = idx >> 6, d = idx & 63;
    float acc = b[d];
#pragma unroll
    for (int f = 0; f < F_IN_; ++f) acc = fmaf(x[n * F_IN_ + f], w[f * DIM_ + d], acc);
    out[idx] = acc > 0.f ? acc : 0.f;
}

// edge MLP layer 1, output TRANSPOSED: h1t[k*E + e] = relu(ea[e,:] @ w1 + b1)[k]
__global__ void mlp1_kernel(const float* __restrict__ ea, const float* __restrict__ w1,
                            const float* __restrict__ b1, float* __restrict__ h1t) {
    int idx = blockIdx.x * blockDim.x + threadIdx.x;
    if (idx >= E_ * MLP_H_) return;
    int k = idx / E_;
    int e = idx - k * E_;
    float acc = b1[k];
#pragma unroll
    for (int f = 0; f < E_FEAT_; ++f) acc = fmaf(ea[e * E_FEAT_ + f], w1[f * MLP_H_ + k], acc);
    h1t[idx] = acc > 0.f ? acc : 0.f;
}

// incoming-edge counts
__global__ void cnt_kernel(const int* __restrict__ dst, float* __restrict__ cnt) {
    int e = blockIdx.x * blockDim.x + threadIdx.x;
    if (e >= E_) return;
    atomicAdd(&cnt[dst[e]], 1.0f);
}

// ew GEMM: ew[le, j] = h1[e0+le, :] @ w2[:, j] + b2[j]   (le in [0, echunk))
// A read from h1t (transposed [128][E]). Tile 64x64, 256 thr, 4x4 microtile, K=128 whole.
__global__ __launch_bounds__(256) void ew_gemm(const float* __restrict__ h1t,
                                               const float* __restrict__ w2,
                                               const float* __restrict__ b2,
                                               float* __restrict__ ew,
                                               int e0, int echunk) {
    __shared__ float As[MLP_H_ * 64];  // As[k*64 + m]
    __shared__ float Bs[MLP_H_ * 64];  // Bs[k*64 + n]
    int m0 = blockIdx.x * 64;
    int n0 = blockIdx.y * 64;
    int tid = threadIdx.x;
    for (int r = 0; r < 32; ++r) {
        int idx = r * 256 + tid;
        int k = idx >> 6;
        int m = idx & 63;
        int gm = m0 + m;
        As[idx] = (gm < echunk) ? h1t[(size_t)k * E_ + e0 + gm] : 0.f;
        Bs[idx] = w2[(size_t)k * EWC_ + n0 + (idx & 63)];
    }
    __syncthreads();
    int tx = tid & 15, ty = tid >> 4;
    float acc[4][4] = {};
    const float4* Av = (const float4*)As;
    const float4* Bv = (const float4*)Bs;
#pragma unroll 8
    for (int k = 0; k < MLP_H_; ++k) {
        float4 a = Av[k * 16 + ty];
        float4 b = Bv[k * 16 + tx];
        acc[0][0] = fmaf(a.x, b.x, acc[0][0]); acc[0][1] = fmaf(a.x, b.y, acc[0][1]);
        acc[0][2] = fmaf(a.x, b.z, acc[0][2]); acc[0][3] = fmaf(a.x, b.w, acc[0][3]);
        acc[1][0] = fmaf(a.y, b.x, acc[1][0]); acc[1][1] = fmaf(a.y, b.y, acc[1][1]);
        acc[1][2] = fmaf(a.y, b.z, acc[1][2]); acc[1][3] = fmaf(a.y, b.w, acc[1][3]);
        acc[2][0] = fmaf(a.z, b.x, acc[2][0]); acc[2][1] = fmaf(a.z, b.y, acc[2][1]);
        acc[2][2] = fmaf(a.z, b.z, acc[2][2]); acc[2][3] = fmaf(a.z, b.w, acc[2][3]);
        acc[3][0] = fmaf(a.w, b.x, acc[3][0]); acc[3][1] = fmaf(a.w, b.y, acc[3][1]);
        acc[3][2] = fmaf(a.w, b.z, acc[3][2]); acc[3][3] = fmaf(a.w, b.w, acc[3][3]);
    }
    float4 bb = *(const float4*)&b2[n0 + tx * 4];
#pragma unroll
    for (int i = 0; i < 4; ++i) {
        int le = m0 + ty * 4 + i;
        if (le < echunk) {
            float4 v;
            v.x = acc[i][0] + bb.x; v.y = acc[i][1] + bb.y;
            v.z = acc[i][2] + bb.z; v.w = acc[i][3] + bb.w;
            *(float4*)&ew[(size_t)le * EWC_ + n0 + tx * 4] = v;
        }
    }
}

// per-edge message: msg[e,o] = sum_i out[src[e],i] * ew[le,i*64+o]; atomic agg on dst
__global__ __launch_bounds__(256) void msg_kernel(const float* __restrict__ ew,
                                                  const int* __restrict__ src,
                                                  const int* __restrict__ dst,
                                                  const float* __restrict__ out,
                                                  float* __restrict__ agg,
                                                  int e0, int echunk) {
    int le = blockIdx.x * 4 + (threadIdx.x >> 6);
    int lane = threadIdx.x & 63;
    if (le >= echunk) return;
    int e = e0 + le;
    int s = src[e], d = dst[e];
    float v = out[s * DIM_ + lane];
    const float* ewr = ew + (size_t)le * EWC_;
    float acc = 0.f;
#pragma unroll 16
    for (int i = 0; i < DIM_; ++i)
        acc = fmaf(__shfl(v, i, 64), ewr[i * DIM_ + lane], acc);
    atomicAdd(&agg[d * DIM_ + lane], acc);
}

// combine (scatter-mean + root + bias + relu) and GRU cell; out==h in place
__global__ __launch_bounds__(256) void gru_kernel(float* __restrict__ out,
                                                  const float* __restrict__ agg,
                                                  const float* __restrict__ cnt,
                                                  const float* __restrict__ root,
                                                  const float* __restrict__ cbias,
                                                  const float* __restrict__ wi,
                                                  const float* __restrict__ wh,
                                                  const float* __restrict__ bi,
                                                  const float* __restrict__ bh) {
    int n = blockIdx.x * 4 + (threadIdx.x >> 6);
    int d = threadIdx.x & 63;
    if (n >= N_) return;
    float h = out[n * DIM_ + d];
    float c = cnt[n]; c = c > 1.f ? c : 1.f;
    float a = agg[n * DIM_ + d] / c;
    float r = 0.f;
#pragma unroll 16
    for (int i = 0; i < DIM_; ++i) r = fmaf(__shfl(h, i, 64), root[i * DIM_ + d], r);
    float m = a + r + cbias[d];
    m = m > 0.f ? m : 0.f;
    float gir = bi[d], giz = bi[64 + d], gin = bi[128 + d];
    float ghr = bh[d], ghz = bh[64 + d], ghn = bh[128 + d];
#pragma unroll 8
    for (int i = 0; i < DIM_; ++i) {
        float mi = __shfl(m, i, 64);
        float hi = __shfl(h, i, 64);
        gir = fmaf(mi, wi[i * 192 + d], gir);
        giz = fmaf(mi, wi[i * 192 + 64 + d], giz);
        gin = fmaf(mi, wi[i * 192 + 128 + d], gin);
        ghr = fmaf(hi, wh[i * 192 + d], ghr);
        ghz = fmaf(hi, wh[i * 192 + 64 + d], ghz);
        ghn = fmaf(hi, wh[i * 192 + 128 + d], ghn);
    }
    float rg = 1.f / (1.f + expf(-(gir + ghr)));
    float zg = 1.f / (1.f + expf(-(giz + ghz)));
    float ng = tanhf(gin + rg * ghn);
    out[n * DIM_ + d] = (1.f - zg) * ng + zg * h;
}

// batch segment offsets
__global__ void count_batch(const int* __restrict__ batch, int* __restrict__ cnt_b) {
    int n = blockIdx.x * blockDim.x + threadIdx.x;
    if (n >= N_) return;
    atomicAdd(&cnt_b[batch[n]], 1);
}
__global__ void scan_off(const int* __restrict__ cnt_b, int* __restrict__ off_b) {
    if (threadIdx.x == 0) {
        int acc = 0;
        off_b[0] = 0;
        for (int b = 0; b < B_; ++b) { acc += cnt_b[b]; off_b[b + 1] = acc; }
    }
}

// Set2Set LSTM cell
__global__ __launch_bounds__(256) void lstm_kernel(const float* __restrict__ q_star,
                                                   float* __restrict__ hl, float* __restrict__ cl,
                                                   const float* __restrict__ wi,
                                                   const float* __restrict__ wh,
                                                   const float* __restrict__ bi,
                                                   const float* __restrict__ bh) {
    int b = blockIdx.x;
    int j = threadIdx.x;  // 0..255
    __shared__ float qs[128], hs[64], g[256];
    if (j < 128) qs[j] = q_star[b * 128 + j];
    if (j < 64) hs[j] = hl[b * 64 + j];
    __syncthreads();
    float acc = bi[j] + bh[j];
#pragma unroll 8
    for (int i = 0; i < 128; ++i) acc = fmaf(qs[i], wi[i * 256 + j], acc);
#pragma unroll 8
    for (int i = 0; i < 64; ++i) acc = fmaf(hs[i], wh[i * 256 + j], acc);
    g[j] = acc;
    __syncthreads();
    if (j < 64) {
        float ig = 1.f / (1.f + expf(-g[j]));
        float fg = 1.f / (1.f + expf(-g[64 + j]));
        float gg = tanhf(g[128 + j]);
        float og = 1.f / (1.f + expf(-g[192 + j]));
        float c = fg * cl[b * 64 + j] + ig * gg;
        cl[b * 64 + j] = c;
        hl[b * 64 + j] = og * tanhf(c);
    }
}

// Set2Set attention: softmax over each graph's nodes, weighted sum -> q_star=[q, r]
__global__ __launch_bounds__(256) void attn_kernel(const float* __restrict__ out,
                                                   const int* __restrict__ off_b,
                                                   const float* __restrict__ hl,
                                                   float* __restrict__ q_star,
                                                   float* __restrict__ e_ws) {
    int b = blockIdx.x;
    int start = off_b[b], end = off_b[b + 1];
    int t = threadIdx.x;
    __shared__ float q[64];
    __shared__ float red[256];
    __shared__ float racc[256];
    __shared__ float sasum[4];
    if (t < 64) q[t] = hl[b * 64 + t];
    __syncthreads();
    float lmax = -1e30f;
    for (int n = start + t; n < end; n += 256) {
        float acc = 0.f;
#pragma unroll 16
        for (int d2 = 0; d2 < 64; ++d2) acc = fmaf(out[n * 64 + d2], q[d2], acc);
        e_ws[n] = acc;
        lmax = fmaxf(lmax, acc);
    }
    red[t] = lmax;
    __syncthreads();
    for (int s2 = 128; s2 > 0; s2 >>= 1) {
        if (t < s2) red[t] = fmaxf(red[t], red[t + s2]);
        __syncthreads();
    }
    float emax = red[0];
    int w = t >> 6, d = t & 63;
    float rl = 0.f, lasum = 0.f;
    for (int n = start + w; n < end; n += 4) {
        float a = expf(e_ws[n] - emax);
        rl = fmaf(a, out[n * 64 + d], rl);
        if (d == 0) lasum += a;
    }
    racc[t] = rl;
    if (d == 0) sasum[w] = lasum;
    __syncthreads();
    if (t < 64) {
        float r = racc[t] + racc[64 + t] + racc[128 + t] + racc[192 + t];
        float as = sasum[0] + sasum[1] + sasum[2] + sasum[3];
        as = fmaxf(as, 1e-16f);
        q_star[b * 128 + t] = q[t];
        q_star[b * 128 + 64 + t] = r / as;
    }
}

// output head: y[b] = relu(q_star[b] @ W1 + b1) @ W2 + b2
__global__ __launch_bounds__(64) void head_kernel(const float* __restrict__ q_star,
                                                  const float* __restrict__ w1,
                                                  const float* __restrict__ b1,
                                                  const float* __restrict__ w2,
                                                  const float* __restrict__ b2,
                                                  float* __restrict__ y) {
    int b = blockIdx.x;
    int d = threadIdx.x;
    float qlo = q_star[b * 128 + d];
    float qhi = q_star[b * 128 + 64 + d];
    float acc = b1[d];
#pragma unroll 8
    for (int i = 0; i < 64; ++i) {
        acc = fmaf(__shfl(qlo, i, 64), w1[i * 64 + d], acc);
        acc = fmaf(__shfl(qhi, i, 64), w1[(64 + i) * 64 + d], acc);
    }
    acc = acc > 0.f ? acc : 0.f;
    float p = acc * w2[d];
    for (int off = 32; off > 0; off >>= 1) p += __shfl_down(p, off, 64);
    if (d == 0) y[b] = p + b2[0];
}

extern "C" void kernel_launch(void* const* d_in, const int* in_sizes, int n_in,
                              void* d_out, int out_size, void* d_ws, size_t ws_size,
                              hipStream_t stream) {
    (void)in_sizes; (void)n_in; (void)out_size;
    const float* x        = (const float*)d_in[0];
    const float* ea       = (const float*)d_in[1];
    const int*   eidx     = (const int*)d_in[2];
    const int*   batch    = (const int*)d_in[3];
    const float* lin0_w   = (const float*)d_in[4];
    const float* lin0_b   = (const float*)d_in[5];
    const float* mlp_w1   = (const float*)d_in[6];
    const float* mlp_b1   = (const float*)d_in[7];
    const float* mlp_w2   = (const float*)d_in[8];
    const float* mlp_b2   = (const float*)d_in[9];
    const float* conv_root= (const float*)d_in[10];
    const float* conv_bias= (const float*)d_in[11];
    const float* gru_wi   = (const float*)d_in[12];
    const float* gru_wh   = (const float*)d_in[13];
    const float* gru_bi   = (const float*)d_in[14];
    const float* gru_bh   = (const float*)d_in[15];
    const float* lstm_wi  = (const float*)d_in[16];
    const float* lstm_wh  = (const float*)d_in[17];
    const float* lstm_bi  = (const float*)d_in[18];
    const float* lstm_bh  = (const float*)d_in[19];
    const float* lin1_w   = (const float*)d_in[20];
    const float* lin1_b   = (const float*)d_in[21];
    const float* lin2_w   = (const float*)d_in[22];
    const float* lin2_b   = (const float*)d_in[23];
    float* y = (float*)d_out;

    const int* src = eidx;
    const int* dst = eidx + E_;

    // workspace carve-up (256B aligned slices)
    char* w = (char*)d_ws;
    auto carve = [&](size_t bytes) {
        char* p = w;
        w += (bytes + 255) & ~(size_t)255;
        return p;
    };
    float* out_buf = (float*)carve((size_t)N_ * DIM_ * 4);
    float* agg     = (float*)carve((size_t)N_ * DIM_ * 4);
    float* cnt     = (float*)carve((size_t)N_ * 4);
    float* e_ws    = (float*)carve((size_t)N_ * 4);
    float* q_star  = (float*)carve((size_t)B_ * 128 * 4);
    float* hl      = (float*)carve((size_t)B_ * 64 * 4);
    float* cl      = (float*)carve((size_t)B_ * 64 * 4);
    int*   cnt_b   = (int*)carve((size_t)B_ * 4);
    int*   off_b   = (int*)carve((size_t)(B_ + 1) * 4);
    float* h1t     = (float*)carve((size_t)E_ * MLP_H_ * 4);
    size_t used = (size_t)(w - (char*)d_ws);
    float* ew = (float*)w;
    size_t avail = ws_size > used ? ws_size - used : 0;
    long long cap = (long long)(avail / ((size_t)EWC_ * 4));
    if (cap > E_) cap = E_;
    cap &= ~63LL;               // multiple of 64
    if (cap < 64) cap = 64;     // assume ws at least this big
    int chunk = (int)cap;
    bool full = (chunk >= E_);

    // init
    hipMemsetAsync(cnt, 0, (size_t)N_ * 4, stream);
    hipMemsetAsync(cnt_b, 0, (size_t)B_ * 4, stream);
    hipMemsetAsync(q_star, 0, (size_t)B_ * 128 * 4, stream);
    hipMemsetAsync(hl, 0, (size_t)B_ * 64 * 4, stream);
    hipMemsetAsync(cl, 0, (size_t)B_ * 64 * 4, stream);

    lin0_kernel<<<(N_ * DIM_ + 255) / 256, 256, 0, stream>>>(x, lin0_w, lin0_b, out_buf);
    mlp1_kernel<<<(E_ * MLP_H_ + 255) / 256, 256, 0, stream>>>(ea, mlp_w1, mlp_b1, h1t);
    cnt_kernel<<<(E_ + 255) / 256, 256, 0, stream>>>(dst, cnt);
    count_batch<<<(N_ + 255) / 256, 256, 0, stream>>>(batch, cnt_b);
    scan_off<<<1, 64, 0, stream>>>(cnt_b, off_b);

    if (full) {
        dim3 g((E_ + 63) / 64, EWC_ / 64);
        ew_gemm<<<g, 256, 0, stream>>>(h1t, mlp_w2, mlp_b2, ew, 0, E_);
    }
    for (int step = 0; step < 3; ++step) {
        hipMemsetAsync(agg, 0, (size_t)N_ * DIM_ * 4, stream);
        if (full) {
            msg_kernel<<<(E_ + 3) / 4, 256, 0, stream>>>(ew, src, dst, out_buf, agg, 0, E_);
        } else {
            for (int e0 = 0; e0 < E_; e0 += chunk) {
                int c = E_ - e0 < chunk ? E_ - e0 : chunk;
                dim3 g((c + 63) / 64, EWC_ / 64);
                ew_gemm<<<g, 256, 0, stream>>>(h1t, mlp_w2, mlp_b2, ew, e0, c);
                msg_kernel<<<(c + 3) / 4, 256, 0, stream>>>(ew, src, dst, out_buf, agg, e0, c);
            }
        }
        gru_kernel<<<(N_ + 3) / 4, 256, 0, stream>>>(out_buf, agg, cnt, conv_root, conv_bias,
                                                     gru_wi, gru_wh, gru_bi, gru_bh);
    }

    for (int s = 0; s < 3; ++s) {
        lstm_kernel<<<B_, 256, 0, stream>>>(q_star, hl, cl, lstm_wi, lstm_wh, lstm_bi, lstm_bh);
        attn_kernel<<<B_, 256, 0, stream>>>(out_buf, off_b, hl, q_star, e_ws);
    }
    head_kernel<<<B_, 64, 0, stream>>>(q_star, lin1_w, lin1_b, lin2_w, lin2_b, y);
}

// Round 2
// 2286.935 us; speedup vs baseline: 4.3726x; 4.3726x over previous
//
#include <hip/hip_runtime.h>
#include <math.h>

// Problem dims (fixed)
#define N_ 20000
#define E_ 100000
#define B_ 128
#define F_IN_ 14
#define DIM_ 64
#define E_FEAT_ 4
#define MLP_H_ 128
#define EWC_ 4096    // DIM*DIM
#define PC_ 8192     // MLP_H * DIM (P columns)

// ---------------------------------------------------------------------------
// lin0: out[n,d] = relu(x[n,:] @ lin0_w + b)
__global__ void lin0_kernel(const float* __restrict__ x, const float* __restrict__ w,
                            const float* __restrict__ b, float* __restrict__ out) {
    int idx = blockIdx.x * blockDim.x + threadIdx.x;
    if (idx >= N_ * DIM_) return;
    int n = idx >> 6, d = idx & 63;
    float acc = b[d];
#pragma unroll
    for (int f = 0; f < F_IN_; ++f) acc = fmaf(x[n * F_IN_ + f], w[f * DIM_ + d], acc);
    out[idx] = acc > 0.f ? acc : 0.f;
}

// edge MLP layer 1, ROW-major: h1[e*128 + k] = relu(ea[e,:] @ w1 + b1)[k]
__global__ void mlp1_kernel(const float* __restrict__ ea, const float* __restrict__ w1,
                            const float* __restrict__ b1, float* __restrict__ h1) {
    int idx = blockIdx.x * blockDim.x + threadIdx.x;
    if (idx >= E_ * MLP_H_) return;
    int e = idx >> 7, k = idx & 127;
    float acc = b1[k];
#pragma unroll
    for (int f = 0; f < E_FEAT_; ++f) acc = fmaf(ea[e * E_FEAT_ + f], w1[f * MLP_H_ + k], acc);
    h1[idx] = acc > 0.f ? acc : 0.f;
}

// incoming-edge counts (float, for mean)
__global__ void cnt_kernel(const int* __restrict__ dst, float* __restrict__ cnt) {
    int e = blockIdx.x * blockDim.x + threadIdx.x;
    if (e >= E_) return;
    atomicAdd(&cnt[dst[e]], 1.0f);
}

// src histogram for counting sort
__global__ void hist_src(const int* __restrict__ src, int* __restrict__ cnt_src) {
    int e = blockIdx.x * blockDim.x + threadIdx.x;
    if (e >= E_) return;
    atomicAdd(&cnt_src[src[e]], 1);
}

// exclusive scan over N_ bins -> src_off[0..N_]
__global__ void scan_src(const int* __restrict__ cnt_src, int* __restrict__ src_off) {
    __shared__ int part[256];
    __shared__ int off[257];
    int t = threadIdx.x;
    const int per = (N_ + 255) / 256;
    int base = t * per;
    int s = 0;
    for (int i = 0; i < per; ++i) { int b = base + i; if (b < N_) s += cnt_src[b]; }
    part[t] = s;
    __syncthreads();
    if (t == 0) {
        int a = 0;
        for (int i = 0; i < 256; ++i) { off[i] = a; a += part[i]; }
        off[256] = a;
    }
    __syncthreads();
    int run = off[t];
    for (int i = 0; i < per; ++i) {
        int b = base + i;
        if (b < N_) { src_off[b] = run; run += cnt_src[b]; }
    }
    if (t == 0) src_off[N_] = off[256];
}

// scatter edges into src-sorted order
__global__ void scatter_src(const int* __restrict__ src, int* __restrict__ cur,
                            const int* __restrict__ src_off, int* __restrict__ eord) {
    int e = blockIdx.x * blockDim.x + threadIdx.x;
    if (e >= E_) return;
    int s = src[e];
    int p = src_off[s] + atomicAdd(&cur[s], 1);
    eord[p] = e;
}

// w2t[i*8192 + k*64 + o] = w2[k*4096 + i*64 + o]
__global__ void transpose_w2(const float* __restrict__ w2, float* __restrict__ w2t) {
    int idx = blockIdx.x * blockDim.x + threadIdx.x;
    if (idx >= 64 * PC_) return;
    int c = idx & (PC_ - 1);          // k*64 + o
    int i = idx >> 13;
    int k = c >> 6, o = c & 63;
    w2t[idx] = w2[k * EWC_ + i * 64 + o];
}

// Q[n,o] = sum_i out[n,i] * b2[i*64+o]   (bias term of per-edge matrices)
__global__ __launch_bounds__(256) void q_kernel(const float* __restrict__ out,
                                                const float* __restrict__ b2,
                                                float* __restrict__ Q) {
    int n = blockIdx.x * 4 + (threadIdx.x >> 6);
    int o = threadIdx.x & 63;
    if (n >= N_) return;
    float v = out[n * 64 + o];
    float acc = 0.f;
#pragma unroll
    for (int i = 0; i < 64; ++i) acc = fmaf(__shfl(v, i, 64), b2[i * 64 + o], acc);
    Q[n * 64 + o] = acc;
}

// P GEMM: P[n-n0, c] = out[n,:] (64) @ w2t[:, c] (64 x 8192), nodes n in [n0,n1).
// Tile: 64 nodes x 256 cols, 256 threads, 8x8 microtile. A staged in LDS
// (k-major, pad 65 -> conflict-free); B streamed from global (w2t = 2 MB,
// L2-resident, reused by all blocks). VALU-bound by design (64 fma per k per
// thread vs ~10 LDS reads).
__global__ __launch_bounds__(256) void p_gemm(const float* __restrict__ out,
                                              const float* __restrict__ w2t,
                                              float* __restrict__ P,
                                              int n0, int n1) {
    __shared__ float As[64 * 65];   // As[k*65 + m]
    int tid = threadIdx.x;
    int mb = blockIdx.y << 6;       // node-tile base within chunk
    int c0 = blockIdx.x << 8;       // col-tile base
    {
        int i = tid & 63;           // K index (coalesced over lanes)
        int m4 = (tid >> 6) << 4;   // 4 groups of 16 rows
        for (int r = 0; r < 16; ++r) {
            int m = m4 + r;
            int gn = n0 + mb + m;
            As[i * 65 + m] = (gn < n1) ? out[(size_t)gn * 64 + i] : 0.f;
        }
    }
    __syncthreads();
    int ty = tid & 7;               // node group (fast) -> A bcast within wave
    int tx = tid >> 3;              // col group [0,32)
    const float* Bp = w2t + c0 + tx * 8;
    float acc[8][8] = {};           // [node j][col]
#pragma unroll 4
    for (int k = 0; k < 64; ++k) {
        float4 b0 = *(const float4*)(Bp + (size_t)k * PC_);
        float4 b1 = *(const float4*)(Bp + (size_t)k * PC_ + 4);
        float a[8];
#pragma unroll
        for (int j = 0; j < 8; ++j) a[j] = As[k * 65 + ty * 8 + j];
#pragma unroll
        for (int j = 0; j < 8; ++j) {
            acc[j][0] = fmaf(a[j], b0.x, acc[j][0]);
            acc[j][1] = fmaf(a[j], b0.y, acc[j][1]);
            acc[j][2] = fmaf(a[j], b0.z, acc[j][2]);
            acc[j][3] = fmaf(a[j], b0.w, acc[j][3]);
            acc[j][4] = fmaf(a[j], b1.x, acc[j][4]);
            acc[j][5] = fmaf(a[j], b1.y, acc[j][5]);
            acc[j][6] = fmaf(a[j], b1.z, acc[j][6]);
            acc[j][7] = fmaf(a[j], b1.w, acc[j][7]);
        }
    }
#pragma unroll
    for (int j = 0; j < 8; ++j) {
        int r = mb + ty * 8 + j;            // chunk-local row
        if (n0 + r < n1) {
            float* pr = P + (size_t)r * PC_ + c0 + tx * 8;
            float4 v0 = { acc[j][0], acc[j][1], acc[j][2], acc[j][3] };
            float4 v1 = { acc[j][4], acc[j][5], acc[j][6], acc[j][7] };
            *(float4*)pr = v0;
            *(float4*)(pr + 4) = v1;
        }
    }
}

// per-edge contraction: msg[e,o] = sum_k h1[e,k]*P[src-n0, k*64+o] + Q[src,o]
// edges taken from src-sorted order, range [src_off[n0], src_off[n1)).
__global__ __launch_bounds__(256) void edge_msg(const float* __restrict__ P,
                                                const float* __restrict__ h1,
                                                const float* __restrict__ Q,
                                                const int* __restrict__ eord,
                                                const int* __restrict__ src,
                                                const int* __restrict__ dst,
                                                const int* __restrict__ src_off,
                                                float* __restrict__ agg,
                                                int n0, int n1) {
    int start = src_off[n0], end = src_off[n1];
    int pos = start + blockIdx.x * 4 + (threadIdx.x >> 6);
    if (pos >= end) return;
    int lane = threadIdx.x & 63;
    int e = eord[pos];
    int s = src[e], d = dst[e];
    const float* Pr = P + (size_t)(s - n0) * PC_;
    float v1 = h1[(size_t)e * 128 + lane];
    float v2 = h1[(size_t)e * 128 + 64 + lane];
    float acc = Q[s * 64 + lane];
#pragma unroll 16
    for (int k = 0; k < 64; ++k)
        acc = fmaf(__shfl(v1, k, 64), Pr[k * 64 + lane], acc);
#pragma unroll 16
    for (int k = 0; k < 64; ++k)
        acc = fmaf(__shfl(v2, k, 64), Pr[(64 + k) * 64 + lane], acc);
    atomicAdd(&agg[d * 64 + lane], acc);
}

// combine (scatter-mean + root + bias + relu) and GRU cell; out==h in place
__global__ __launch_bounds__(256) void gru_kernel(float* __restrict__ out,
                                                  const float* __restrict__ agg,
                                                  const float* __restrict__ cnt,
                                                  const float* __restrict__ root,
                                                  const float* __restrict__ cbias,
                                                  const float* __restrict__ wi,
                                                  const float* __restrict__ wh,
                                                  const float* __restrict__ bi,
                                                  const float* __restrict__ bh) {
    int n = blockIdx.x * 4 + (threadIdx.x >> 6);
    int d = threadIdx.x & 63;
    if (n >= N_) return;
    float h = out[n * DIM_ + d];
    float c = cnt[n]; c = c > 1.f ? c : 1.f;
    float a = agg[n * DIM_ + d] / c;
    float r = 0.f;
#pragma unroll 16
    for (int i = 0; i < DIM_; ++i) r = fmaf(__shfl(h, i, 64), root[i * DIM_ + d], r);
    float m = a + r + cbias[d];
    m = m > 0.f ? m : 0.f;
    float gir = bi[d], giz = bi[64 + d], gin = bi[128 + d];
    float ghr = bh[d], ghz = bh[64 + d], ghn = bh[128 + d];
#pragma unroll 8
    for (int i = 0; i < DIM_; ++i) {
        float mi = __shfl(m, i, 64);
        float hi = __shfl(h, i, 64);
        gir = fmaf(mi, wi[i * 192 + d], gir);
        giz = fmaf(mi, wi[i * 192 + 64 + d], giz);
        gin = fmaf(mi, wi[i * 192 + 128 + d], gin);
        ghr = fmaf(hi, wh[i * 192 + d], ghr);
        ghz = fmaf(hi, wh[i * 192 + 64 + d], ghz);
        ghn = fmaf(hi, wh[i * 192 + 128 + d], ghn);
    }
    float rg = 1.f / (1.f + expf(-(gir + ghr)));
    float zg = 1.f / (1.f + expf(-(giz + ghz)));
    float ng = tanhf(gin + rg * ghn);
    out[n * DIM_ + d] = (1.f - zg) * ng + zg * h;
}

// batch segment offsets
__global__ void count_batch(const int* __restrict__ batch, int* __restrict__ cnt_b) {
    int n = blockIdx.x * blockDim.x + threadIdx.x;
    if (n >= N_) return;
    atomicAdd(&cnt_b[batch[n]], 1);
}
__global__ void scan_off(const int* __restrict__ cnt_b, int* __restrict__ off_b) {
    if (threadIdx.x == 0) {
        int acc = 0;
        off_b[0] = 0;
        for (int b = 0; b < B_; ++b) { acc += cnt_b[b]; off_b[b + 1] = acc; }
    }
}

// Set2Set LSTM cell
__global__ __launch_bounds__(256) void lstm_kernel(const float* __restrict__ q_star,
                                                   float* __restrict__ hl, float* __restrict__ cl,
                                                   const float* __restrict__ wi,
                                                   const float* __restrict__ wh,
                                                   const float* __restrict__ bi,
                                                   const float* __restrict__ bh) {
    int b = blockIdx.x;
    int j = threadIdx.x;
    __shared__ float qs[128], hs[64], g[256];
    if (j < 128) qs[j] = q_star[b * 128 + j];
    if (j < 64) hs[j] = hl[b * 64 + j];
    __syncthreads();
    float acc = bi[j] + bh[j];
#pragma unroll 8
    for (int i = 0; i < 128; ++i) acc = fmaf(qs[i], wi[i * 256 + j], acc);
#pragma unroll 8
    for (int i = 0; i < 64; ++i) acc = fmaf(hs[i], wh[i * 256 + j], acc);
    g[j] = acc;
    __syncthreads();
    if (j < 64) {
        float ig = 1.f / (1.f + expf(-g[j]));
        float fg = 1.f / (1.f + expf(-g[64 + j]));
        float gg = tanhf(g[128 + j]);
        float og = 1.f / (1.f + expf(-g[192 + j]));
        float c = fg * cl[b * 64 + j] + ig * gg;
        cl[b * 64 + j] = c;
        hl[b * 64 + j] = og * tanhf(c);
    }
}

// Set2Set attention
__global__ __launch_bounds__(256) void attn_kernel(const float* __restrict__ out,
                                                   const int* __restrict__ off_b,
                                                   const float* __restrict__ hl,
                                                   float* __restrict__ q_star,
                                                   float* __restrict__ e_ws) {
    int b = blockIdx.x;
    int start = off_b[b], end = off_b[b + 1];
    int t = threadIdx.x;
    __shared__ float q[64];
    __shared__ float red[256];
    __shared__ float racc[256];
    __shared__ float sasum[4];
    if (t < 64) q[t] = hl[b * 64 + t];
    __syncthreads();
    float lmax = -1e30f;
    for (int n = start + t; n < end; n += 256) {
        float acc = 0.f;
#pragma unroll 16
        for (int d2 = 0; d2 < 64; ++d2) acc = fmaf(out[n * 64 + d2], q[d2], acc);
        e_ws[n] = acc;
        lmax = fmaxf(lmax, acc);
    }
    red[t] = lmax;
    __syncthreads();
    for (int s2 = 128; s2 > 0; s2 >>= 1) {
        if (t < s2) red[t] = fmaxf(red[t], red[t + s2]);
        __syncthreads();
    }
    float emax = red[0];
    int w = t >> 6, d = t & 63;
    float rl = 0.f, lasum = 0.f;
    for (int n = start + w; n < end; n += 4) {
        float a = expf(e_ws[n] - emax);
        rl = fmaf(a, out[n * 64 + d], rl);
        if (d == 0) lasum += a;
    }
    racc[t] = rl;
    if (d == 0) sasum[w] = lasum;
    __syncthreads();
    if (t < 64) {
        float r = racc[t] + racc[64 + t] + racc[128 + t] + racc[192 + t];
        float as = sasum[0] + sasum[1] + sasum[2] + sasum[3];
        as = fmaxf(as, 1e-16f);
        q_star[b * 128 + t] = q[t];
        q_star[b * 128 + 64 + t] = r / as;
    }
}

// output head
__global__ __launch_bounds__(64) void head_kernel(const float* __restrict__ q_star,
                                                  const float* __restrict__ w1,
                                                  const float* __restrict__ b1,
                                                  const float* __restrict__ w2,
                                                  const float* __restrict__ b2,
                                                  float* __restrict__ y) {
    int b = blockIdx.x;
    int d = threadIdx.x;
    float qlo = q_star[b * 128 + d];
    float qhi = q_star[b * 128 + 64 + d];
    float acc = b1[d];
#pragma unroll 8
    for (int i = 0; i < 64; ++i) {
        acc = fmaf(__shfl(qlo, i, 64), w1[i * 64 + d], acc);
        acc = fmaf(__shfl(qhi, i, 64), w1[(64 + i) * 64 + d], acc);
    }
    acc = acc > 0.f ? acc : 0.f;
    float p = acc * w2[d];
    for (int off = 32; off > 0; off >>= 1) p += __shfl_down(p, off, 64);
    if (d == 0) y[b] = p + b2[0];
}

extern "C" void kernel_launch(void* const* d_in, const int* in_sizes, int n_in,
                              void* d_out, int out_size, void* d_ws, size_t ws_size,
                              hipStream_t stream) {
    (void)in_sizes; (void)n_in; (void)out_size;
    const float* x        = (const float*)d_in[0];
    const float* ea       = (const float*)d_in[1];
    const int*   eidx     = (const int*)d_in[2];
    const int*   batch    = (const int*)d_in[3];
    const float* lin0_w   = (const float*)d_in[4];
    const float* lin0_b   = (const float*)d_in[5];
    const float* mlp_w1   = (const float*)d_in[6];
    const float* mlp_b1   = (const float*)d_in[7];
    const float* mlp_w2   = (const float*)d_in[8];
    const float* mlp_b2   = (const float*)d_in[9];
    const float* conv_root= (const float*)d_in[10];
    const float* conv_bias= (const float*)d_in[11];
    const float* gru_wi   = (const float*)d_in[12];
    const float* gru_wh   = (const float*)d_in[13];
    const float* gru_bi   = (const float*)d_in[14];
    const float* gru_bh   = (const float*)d_in[15];
    const float* lstm_wi  = (const float*)d_in[16];
    const float* lstm_wh  = (const float*)d_in[17];
    const float* lstm_bi  = (const float*)d_in[18];
    const float* lstm_bh  = (const float*)d_in[19];
    const float* lin1_w   = (const float*)d_in[20];
    const float* lin1_b   = (const float*)d_in[21];
    const float* lin2_w   = (const float*)d_in[22];
    const float* lin2_b   = (const float*)d_in[23];
    float* y = (float*)d_out;

    const int* src = eidx;
    const int* dst = eidx + E_;

    char* w = (char*)d_ws;
    auto carve = [&](size_t bytes) {
        char* p = w;
        w += (bytes + 255) & ~(size_t)255;
        return p;
    };
    float* out_buf = (float*)carve((size_t)N_ * DIM_ * 4);
    float* agg     = (float*)carve((size_t)N_ * DIM_ * 4);
    float* Q       = (float*)carve((size_t)N_ * DIM_ * 4);
    float* cnt     = (float*)carve((size_t)N_ * 4);
    float* e_ws    = (float*)carve((size_t)N_ * 4);
    float* q_star  = (float*)carve((size_t)B_ * 128 * 4);
    float* hl      = (float*)carve((size_t)B_ * 64 * 4);
    float* cl      = (float*)carve((size_t)B_ * 64 * 4);
    int*   cnt_b   = (int*)carve((size_t)B_ * 4);
    int*   off_b   = (int*)carve((size_t)(B_ + 1) * 4);
    float* h1      = (float*)carve((size_t)E_ * MLP_H_ * 4);
    float* w2t     = (float*)carve((size_t)64 * PC_ * 4);
    int*   cnt_src = (int*)carve((size_t)N_ * 4);
    int*   src_off = (int*)carve((size_t)(N_ + 1) * 4);
    int*   cur     = (int*)carve((size_t)N_ * 4);
    int*   eord    = (int*)carve((size_t)E_ * 4);
    size_t used = (size_t)(w - (char*)d_ws);
    float* P = (float*)w;
    size_t avail = ws_size > used ? ws_size - used : 0;
    long long nc = (long long)(avail / ((size_t)PC_ * 4));
    if (nc > N_) nc = N_;
    nc &= ~63LL;
    if (nc < 64) nc = 64;           // assume ws at least this big
    int NC = (int)nc;

    // init
    hipMemsetAsync(cnt, 0, (size_t)N_ * 4, stream);
    hipMemsetAsync(cnt_b, 0, (size_t)B_ * 4, stream);
    hipMemsetAsync(cnt_src, 0, (size_t)N_ * 4, stream);
    hipMemsetAsync(cur, 0, (size_t)N_ * 4, stream);
    hipMemsetAsync(q_star, 0, (size_t)B_ * 128 * 4, stream);
    hipMemsetAsync(hl, 0, (size_t)B_ * 64 * 4, stream);
    hipMemsetAsync(cl, 0, (size_t)B_ * 64 * 4, stream);

    lin0_kernel<<<(N_ * DIM_ + 255) / 256, 256, 0, stream>>>(x, lin0_w, lin0_b, out_buf);
    mlp1_kernel<<<(E_ * MLP_H_ + 255) / 256, 256, 0, stream>>>(ea, mlp_w1, mlp_b1, h1);
    cnt_kernel<<<(E_ + 255) / 256, 256, 0, stream>>>(dst, cnt);
    count_batch<<<(N_ + 255) / 256, 256, 0, stream>>>(batch, cnt_b);
    scan_off<<<1, 64, 0, stream>>>(cnt_b, off_b);
    hist_src<<<(E_ + 255) / 256, 256, 0, stream>>>(src, cnt_src);
    scan_src<<<1, 256, 0, stream>>>(cnt_src, src_off);
    scatter_src<<<(E_ + 255) / 256, 256, 0, stream>>>(src, cur, src_off, eord);
    transpose_w2<<<(64 * PC_ + 255) / 256, 256, 0, stream>>>(mlp_w2, w2t);

    for (int step = 0; step < 3; ++step) {
        q_kernel<<<(N_ + 3) / 4, 256, 0, stream>>>(out_buf, mlp_b2, Q);
        hipMemsetAsync(agg, 0, (size_t)N_ * DIM_ * 4, stream);
        for (int n0 = 0; n0 < N_; n0 += NC) {
            int n1 = n0 + NC < N_ ? n0 + NC : N_;
            dim3 g(PC_ / 256, (n1 - n0 + 63) / 64);
            p_gemm<<<g, 256, 0, stream>>>(out_buf, w2t, P, n0, n1);
            edge_msg<<<(E_ + 3) / 4, 256, 0, stream>>>(P, h1, Q, eord, src, dst,
                                                       src_off, agg, n0, n1);
        }
        gru_kernel<<<(N_ + 3) / 4, 256, 0, stream>>>(out_buf, agg, cnt, conv_root, conv_bias,
                                                     gru_wi, gru_wh, gru_bi, gru_bh);
    }

    for (int s = 0; s < 3; ++s) {
        lstm_kernel<<<B_, 256, 0, stream>>>(q_star, hl, cl, lstm_wi, lstm_wh, lstm_bi, lstm_bh);
        attn_kernel<<<B_, 256, 0, stream>>>(out_buf, off_b, hl, q_star, e_ws);
    }
    head_kernel<<<B_, 64, 0, stream>>>(q_star, lin1_w, lin1_b, lin2_w, lin2_b, y);
}

// Round 3
// 1716.275 us; speedup vs baseline: 5.8265x; 1.3325x over previous
//
#include <hip/hip_runtime.h>
#include <math.h>

// Problem dims (fixed)
#define N_ 20000
#define E_ 100000
#define B_ 128
#define F_IN_ 14
#define DIM_ 64
#define E_FEAT_ 4
#define MLP_H_ 128
#define EWC_ 4096    // DIM*DIM
#define PC_ 8192     // MLP_H * DIM (P columns)

typedef __attribute__((ext_vector_type(8))) short bf16x8;
typedef __attribute__((ext_vector_type(4))) float f32x4;

__device__ __forceinline__ unsigned short f2bf_rn(float f) {
    unsigned int u = __float_as_uint(f);
    unsigned int r = (u + 0x7fffu + ((u >> 16) & 1u)) >> 16;
    return (unsigned short)r;
}
__device__ __forceinline__ float bf2f(unsigned short h) {
    return __uint_as_float(((unsigned int)h) << 16);
}

// ---------------------------------------------------------------------------
// lin0: out[n,d] = relu(x[n,:] @ lin0_w + b)
__global__ void lin0_kernel(const float* __restrict__ x, const float* __restrict__ w,
                            const float* __restrict__ b, float* __restrict__ out) {
    int idx = blockIdx.x * blockDim.x + threadIdx.x;
    if (idx >= N_ * DIM_) return;
    int n = idx >> 6, d = idx & 63;
    float acc = b[d];
#pragma unroll
    for (int f = 0; f < F_IN_; ++f) acc = fmaf(x[n * F_IN_ + f], w[f * DIM_ + d], acc);
    out[idx] = acc > 0.f ? acc : 0.f;
}

// edge MLP layer 1, ROW-major: h1[e*128 + k] = relu(ea[e,:] @ w1 + b1)[k]
__global__ void mlp1_kernel(const float* __restrict__ ea, const float* __restrict__ w1,
                            const float* __restrict__ b1, float* __restrict__ h1) {
    int idx = blockIdx.x * blockDim.x + threadIdx.x;
    if (idx >= E_ * MLP_H_) return;
    int e = idx >> 7, k = idx & 127;
    float acc = b1[k];
#pragma unroll
    for (int f = 0; f < E_FEAT_; ++f) acc = fmaf(ea[e * E_FEAT_ + f], w1[f * MLP_H_ + k], acc);
    h1[idx] = acc > 0.f ? acc : 0.f;
}

// incoming-edge counts (float, for mean)
__global__ void cnt_kernel(const int* __restrict__ dst, float* __restrict__ cnt) {
    int e = blockIdx.x * blockDim.x + threadIdx.x;
    if (e >= E_) return;
    atomicAdd(&cnt[dst[e]], 1.0f);
}

// src histogram for counting sort
__global__ void hist_src(const int* __restrict__ src, int* __restrict__ cnt_src) {
    int e = blockIdx.x * blockDim.x + threadIdx.x;
    if (e >= E_) return;
    atomicAdd(&cnt_src[src[e]], 1);
}

// exclusive scan over N_ bins -> src_off[0..N_]
__global__ void scan_src(const int* __restrict__ cnt_src, int* __restrict__ src_off) {
    __shared__ int part[256];
    __shared__ int off[257];
    int t = threadIdx.x;
    const int per = (N_ + 255) / 256;
    int base = t * per;
    int s = 0;
    for (int i = 0; i < per; ++i) { int b = base + i; if (b < N_) s += cnt_src[b]; }
    part[t] = s;
    __syncthreads();
    if (t == 0) {
        int a = 0;
        for (int i = 0; i < 256; ++i) { off[i] = a; a += part[i]; }
        off[256] = a;
    }
    __syncthreads();
    int run = off[t];
    for (int i = 0; i < per; ++i) {
        int b = base + i;
        if (b < N_) { src_off[b] = run; run += cnt_src[b]; }
    }
    if (t == 0) src_off[N_] = off[256];
}

// scatter edges into src-sorted order
__global__ void scatter_src(const int* __restrict__ src, int* __restrict__ cur,
                            const int* __restrict__ src_off, int* __restrict__ eord) {
    int e = blockIdx.x * blockDim.x + threadIdx.x;
    if (e >= E_) return;
    int s = src[e];
    int p = src_off[s] + atomicAdd(&cur[s], 1);
    eord[p] = e;
}

// B prep (once): Bh/Bl[c*64 + i] = bf16 hi/lo of w2[(c>>6)*4096 + i*64 + (c&63)]
__global__ void prep_b(const float* __restrict__ w2,
                       unsigned short* __restrict__ Bh,
                       unsigned short* __restrict__ Bl) {
    int idx = blockIdx.x * blockDim.x + threadIdx.x;
    if (idx >= PC_ * 64) return;
    int c = idx >> 6, i = idx & 63;
    float v = w2[(size_t)(c >> 6) * EWC_ + i * 64 + (c & 63)];
    unsigned short h = f2bf_rn(v);
    Bh[idx] = h;
    Bl[idx] = f2bf_rn(v - bf2f(h));
}

// Q[n,o] = sum_i out[n,i] * b2[i*64+o]   (bias term of per-edge matrices)
__global__ __launch_bounds__(256) void q_kernel(const float* __restrict__ out,
                                                const float* __restrict__ b2,
                                                float* __restrict__ Q) {
    int n = blockIdx.x * 4 + (threadIdx.x >> 6);
    int o = threadIdx.x & 63;
    if (n >= N_) return;
    float v = out[n * 64 + o];
    float acc = 0.f;
#pragma unroll
    for (int i = 0; i < 64; ++i) acc = fmaf(__shfl(v, i, 64), b2[i * 64 + o], acc);
    Q[n * 64 + o] = acc;
}

// ---------------------------------------------------------------------------
// P GEMM via split-bf16 MFMA: P[r, c] = out[n0+r,:] (64) @ B[64 x 8192]
// 3-term: Ah*Bh + Al*Bh + Ah*Bl  (al*bl dropped, ~2^-18 rel err).
// Block 128x128 tile, 4 waves of 64x64, one-shot K=64 (no k-loop).
// LDS rows padded 64->72 bf16 so frag ds_read_b128 is conflict-free.
#define LSTR 72
__global__ __launch_bounds__(256) void p_gemm_mfma(const float* __restrict__ out,
                                                   const unsigned short* __restrict__ Bh,
                                                   const unsigned short* __restrict__ Bl,
                                                   float* __restrict__ P,
                                                   int n0, int n1) {
    __shared__ unsigned short Ah_s[128 * LSTR];
    __shared__ unsigned short Al_s[128 * LSTR];
    __shared__ unsigned short Bh_s[128 * LSTR];
    __shared__ unsigned short Bl_s[128 * LSTR];
    int tid = threadIdx.x;
    int mloc0 = blockIdx.y * 128;        // chunk-local node row base
    int nbase = blockIdx.x * 128;        // col base

    // stage A (128 rows x 64 k fp32 -> hi/lo bf16), 4 elems/thread/iter
#pragma unroll
    for (int it = 0; it < 8; ++it) {
        int i = it * 1024 + tid * 4;
        int m = i >> 6, k = i & 63;
        int gm = n0 + mloc0 + m;
        float4 v = {0.f, 0.f, 0.f, 0.f};
        if (gm < n1) v = *(const float4*)&out[(size_t)gm * 64 + k];
        unsigned short h0 = f2bf_rn(v.x), h1v = f2bf_rn(v.y),
                       h2 = f2bf_rn(v.z), h3 = f2bf_rn(v.w);
        ushort4 hv = {h0, h1v, h2, h3};
        ushort4 lv = {f2bf_rn(v.x - bf2f(h0)), f2bf_rn(v.y - bf2f(h1v)),
                      f2bf_rn(v.z - bf2f(h2)), f2bf_rn(v.w - bf2f(h3))};
        *(ushort4*)&Ah_s[m * LSTR + k] = hv;
        *(ushort4*)&Al_s[m * LSTR + k] = lv;
    }
    // stage B (128 n-rows x 64 k bf16), 8 elems/thread/iter
#pragma unroll
    for (int it = 0; it < 4; ++it) {
        int i = it * 2048 + tid * 8;
        int n = i >> 6, k = i & 63;
        size_t g = (size_t)(nbase + n) * 64 + k;
        *(int4*)&Bh_s[n * LSTR + k] = *(const int4*)&Bh[g];
        *(int4*)&Bl_s[n * LSTR + k] = *(const int4*)&Bl[g];
    }
    __syncthreads();

    int lane = tid & 63;
    int wid = tid >> 6;
    int wm = (wid & 1) * 64;             // wave row offset in tile
    int wn = (wid >> 1) * 64;            // wave col offset in tile
    int lrow = lane & 15;
    int quad = lane >> 4;

    // B fragments: [nf][ks]
    bf16x8 bhf[4][2], blf[4][2];
#pragma unroll
    for (int nf = 0; nf < 4; ++nf)
#pragma unroll
        for (int ks = 0; ks < 2; ++ks) {
            int row = wn + nf * 16 + lrow;
            int col = ks * 32 + quad * 8;
            bhf[nf][ks] = *(const bf16x8*)&Bh_s[row * LSTR + col];
            blf[nf][ks] = *(const bf16x8*)&Bl_s[row * LSTR + col];
        }

    f32x4 acc[4][4];
#pragma unroll
    for (int a = 0; a < 4; ++a)
#pragma unroll
        for (int b = 0; b < 4; ++b) acc[a][b] = (f32x4){0.f, 0.f, 0.f, 0.f};

#pragma unroll
    for (int mf = 0; mf < 4; ++mf) {
        bf16x8 ahf[2], alf[2];
#pragma unroll
        for (int ks = 0; ks < 2; ++ks) {
            int row = wm + mf * 16 + lrow;
            int col = ks * 32 + quad * 8;
            ahf[ks] = *(const bf16x8*)&Ah_s[row * LSTR + col];
            alf[ks] = *(const bf16x8*)&Al_s[row * LSTR + col];
        }
#pragma unroll
        for (int nf = 0; nf < 4; ++nf) {
#pragma unroll
            for (int ks = 0; ks < 2; ++ks) {
                acc[mf][nf] = __builtin_amdgcn_mfma_f32_16x16x32_bf16(
                    ahf[ks], bhf[nf][ks], acc[mf][nf], 0, 0, 0);
                acc[mf][nf] = __builtin_amdgcn_mfma_f32_16x16x32_bf16(
                    alf[ks], bhf[nf][ks], acc[mf][nf], 0, 0, 0);
                acc[mf][nf] = __builtin_amdgcn_mfma_f32_16x16x32_bf16(
                    ahf[ks], blf[nf][ks], acc[mf][nf], 0, 0, 0);
            }
        }
    }

    // epilogue: C/D frag layout col=lane&15, row=quad*4+reg (m89-verified)
#pragma unroll
    for (int mf = 0; mf < 4; ++mf)
#pragma unroll
        for (int nf = 0; nf < 4; ++nf)
#pragma unroll
            for (int r = 0; r < 4; ++r) {
                int mloc = mloc0 + wm + mf * 16 + quad * 4 + r;
                if (n0 + mloc < n1)
                    P[(size_t)mloc * PC_ + nbase + wn + nf * 16 + lrow] = acc[mf][nf][r];
            }
}

// per-edge contraction: msg[e,o] = sum_k h1[e,k]*P[src-n0, k*64+o] + Q[src,o]
__global__ __launch_bounds__(256) void edge_msg(const float* __restrict__ P,
                                                const float* __restrict__ h1,
                                                const float* __restrict__ Q,
                                                const int* __restrict__ eord,
                                                const int* __restrict__ src,
                                                const int* __restrict__ dst,
                                                const int* __restrict__ src_off,
                                                float* __restrict__ agg,
                                                int n0, int n1) {
    int start = src_off[n0], end = src_off[n1];
    int pos = start + blockIdx.x * 4 + (threadIdx.x >> 6);
    if (pos >= end) return;
    int lane = threadIdx.x & 63;
    int e = eord[pos];
    int s = src[e], d = dst[e];
    const float* Pr = P + (size_t)(s - n0) * PC_;
    float v1 = h1[(size_t)e * 128 + lane];
    float v2 = h1[(size_t)e * 128 + 64 + lane];
    float acc = Q[s * 64 + lane];
#pragma unroll 16
    for (int k = 0; k < 64; ++k)
        acc = fmaf(__shfl(v1, k, 64), Pr[k * 64 + lane], acc);
#pragma unroll 16
    for (int k = 0; k < 64; ++k)
        acc = fmaf(__shfl(v2, k, 64), Pr[(64 + k) * 64 + lane], acc);
    atomicAdd(&agg[d * 64 + lane], acc);
}

// combine (scatter-mean + root + bias + relu) and GRU cell; out==h in place
__global__ __launch_bounds__(256) void gru_kernel(float* __restrict__ out,
                                                  const float* __restrict__ agg,
                                                  const float* __restrict__ cnt,
                                                  const float* __restrict__ root,
                                                  const float* __restrict__ cbias,
                                                  const float* __restrict__ wi,
                                                  const float* __restrict__ wh,
                                                  const float* __restrict__ bi,
                                                  const float* __restrict__ bh) {
    int n = blockIdx.x * 4 + (threadIdx.x >> 6);
    int d = threadIdx.x & 63;
    if (n >= N_) return;
    float h = out[n * DIM_ + d];
    float c = cnt[n]; c = c > 1.f ? c : 1.f;
    float a = agg[n * DIM_ + d] / c;
    float r = 0.f;
#pragma unroll 16
    for (int i = 0; i < DIM_; ++i) r = fmaf(__shfl(h, i, 64), root[i * DIM_ + d], r);
    float m = a + r + cbias[d];
    m = m > 0.f ? m : 0.f;
    float gir = bi[d], giz = bi[64 + d], gin = bi[128 + d];
    float ghr = bh[d], ghz = bh[64 + d], ghn = bh[128 + d];
#pragma unroll 8
    for (int i = 0; i < DIM_; ++i) {
        float mi = __shfl(m, i, 64);
        float hi = __shfl(h, i, 64);
        gir = fmaf(mi, wi[i * 192 + d], gir);
        giz = fmaf(mi, wi[i * 192 + 64 + d], giz);
        gin = fmaf(mi, wi[i * 192 + 128 + d], gin);
        ghr = fmaf(hi, wh[i * 192 + d], ghr);
        ghz = fmaf(hi, wh[i * 192 + 64 + d], ghz);
        ghn = fmaf(hi, wh[i * 192 + 128 + d], ghn);
    }
    float rg = 1.f / (1.f + expf(-(gir + ghr)));
    float zg = 1.f / (1.f + expf(-(giz + ghz)));
    float ng = tanhf(gin + rg * ghn);
    out[n * DIM_ + d] = (1.f - zg) * ng + zg * h;
}

// batch segment offsets
__global__ void count_batch(const int* __restrict__ batch, int* __restrict__ cnt_b) {
    int n = blockIdx.x * blockDim.x + threadIdx.x;
    if (n >= N_) return;
    atomicAdd(&cnt_b[batch[n]], 1);
}
__global__ void scan_off(const int* __restrict__ cnt_b, int* __restrict__ off_b) {
    if (threadIdx.x == 0) {
        int acc = 0;
        off_b[0] = 0;
        for (int b = 0; b < B_; ++b) { acc += cnt_b[b]; off_b[b + 1] = acc; }
    }
}

// Set2Set LSTM cell
__global__ __launch_bounds__(256) void lstm_kernel(const float* __restrict__ q_star,
                                                   float* __restrict__ hl, float* __restrict__ cl,
                                                   const float* __restrict__ wi,
                                                   const float* __restrict__ wh,
                                                   const float* __restrict__ bi,
                                                   const float* __restrict__ bh) {
    int b = blockIdx.x;
    int j = threadIdx.x;
    __shared__ float qs[128], hs[64], g[256];
    if (j < 128) qs[j] = q_star[b * 128 + j];
    if (j < 64) hs[j] = hl[b * 64 + j];
    __syncthreads();
    float acc = bi[j] + bh[j];
#pragma unroll 8
    for (int i = 0; i < 128; ++i) acc = fmaf(qs[i], wi[i * 256 + j], acc);
#pragma unroll 8
    for (int i = 0; i < 64; ++i) acc = fmaf(hs[i], wh[i * 256 + j], acc);
    g[j] = acc;
    __syncthreads();
    if (j < 64) {
        float ig = 1.f / (1.f + expf(-g[j]));
        float fg = 1.f / (1.f + expf(-g[64 + j]));
        float gg = tanhf(g[128 + j]);
        float og = 1.f / (1.f + expf(-g[192 + j]));
        float c = fg * cl[b * 64 + j] + ig * gg;
        cl[b * 64 + j] = c;
        hl[b * 64 + j] = og * tanhf(c);
    }
}

// Set2Set attention
__global__ __launch_bounds__(256) void attn_kernel(const float* __restrict__ out,
                                                   const int* __restrict__ off_b,
                                                   const float* __restrict__ hl,
                                                   float* __restrict__ q_star,
                                                   float* __restrict__ e_ws) {
    int b = blockIdx.x;
    int start = off_b[b], end = off_b[b + 1];
    int t = threadIdx.x;
    __shared__ float q[64];
    __shared__ float red[256];
    __shared__ float racc[256];
    __shared__ float sasum[4];
    if (t < 64) q[t] = hl[b * 64 + t];
    __syncthreads();
    float lmax = -1e30f;
    for (int n = start + t; n < end; n += 256) {
        float acc = 0.f;
#pragma unroll 16
        for (int d2 = 0; d2 < 64; ++d2) acc = fmaf(out[n * 64 + d2], q[d2], acc);
        e_ws[n] = acc;
        lmax = fmaxf(lmax, acc);
    }
    red[t] = lmax;
    __syncthreads();
    for (int s2 = 128; s2 > 0; s2 >>= 1) {
        if (t < s2) red[t] = fmaxf(red[t], red[t + s2]);
        __syncthreads();
    }
    float emax = red[0];
    int w = t >> 6, d = t & 63;
    float rl = 0.f, lasum = 0.f;
    for (int n = start + w; n < end; n += 4) {
        float a = expf(e_ws[n] - emax);
        rl = fmaf(a, out[n * 64 + d], rl);
        if (d == 0) lasum += a;
    }
    racc[t] = rl;
    if (d == 0) sasum[w] = lasum;
    __syncthreads();
    if (t < 64) {
        float r = racc[t] + racc[64 + t] + racc[128 + t] + racc[192 + t];
        float as = sasum[0] + sasum[1] + sasum[2] + sasum[3];
        as = fmaxf(as, 1e-16f);
        q_star[b * 128 + t] = q[t];
        q_star[b * 128 + 64 + t] = r / as;
    }
}

// output head
__global__ __launch_bounds__(64) void head_kernel(const float* __restrict__ q_star,
                                                  const float* __restrict__ w1,
                                                  const float* __restrict__ b1,
                                                  const float* __restrict__ w2,
                                                  const float* __restrict__ b2,
                                                  float* __restrict__ y) {
    int b = blockIdx.x;
    int d = threadIdx.x;
    float qlo = q_star[b * 128 + d];
    float qhi = q_star[b * 128 + 64 + d];
    float acc = b1[d];
#pragma unroll 8
    for (int i = 0; i < 64; ++i) {
        acc = fmaf(__shfl(qlo, i, 64), w1[i * 64 + d], acc);
        acc = fmaf(__shfl(qhi, i, 64), w1[(64 + i) * 64 + d], acc);
    }
    acc = acc > 0.f ? acc : 0.f;
    float p = acc * w2[d];
    for (int off = 32; off > 0; off >>= 1) p += __shfl_down(p, off, 64);
    if (d == 0) y[b] = p + b2[0];
}

extern "C" void kernel_launch(void* const* d_in, const int* in_sizes, int n_in,
                              void* d_out, int out_size, void* d_ws, size_t ws_size,
                              hipStream_t stream) {
    (void)in_sizes; (void)n_in; (void)out_size;
    const float* x        = (const float*)d_in[0];
    const float* ea       = (const float*)d_in[1];
    const int*   eidx     = (const int*)d_in[2];
    const int*   batch    = (const int*)d_in[3];
    const float* lin0_w   = (const float*)d_in[4];
    const float* lin0_b   = (const float*)d_in[5];
    const float* mlp_w1   = (const float*)d_in[6];
    const float* mlp_b1   = (const float*)d_in[7];
    const float* mlp_w2   = (const float*)d_in[8];
    const float* mlp_b2   = (const float*)d_in[9];
    const float* conv_root= (const float*)d_in[10];
    const float* conv_bias= (const float*)d_in[11];
    const float* gru_wi   = (const float*)d_in[12];
    const float* gru_wh   = (const float*)d_in[13];
    const float* gru_bi   = (const float*)d_in[14];
    const float* gru_bh   = (const float*)d_in[15];
    const float* lstm_wi  = (const float*)d_in[16];
    const float* lstm_wh  = (const float*)d_in[17];
    const float* lstm_bi  = (const float*)d_in[18];
    const float* lstm_bh  = (const float*)d_in[19];
    const float* lin1_w   = (const float*)d_in[20];
    const float* lin1_b   = (const float*)d_in[21];
    const float* lin2_w   = (const float*)d_in[22];
    const float* lin2_b   = (const float*)d_in[23];
    float* y = (float*)d_out;

    const int* src = eidx;
    const int* dst = eidx + E_;

    char* w = (char*)d_ws;
    auto carve = [&](size_t bytes) {
        char* p = w;
        w += (bytes + 255) & ~(size_t)255;
        return p;
    };
    float* out_buf = (float*)carve((size_t)N_ * DIM_ * 4);
    float* agg     = (float*)carve((size_t)N_ * DIM_ * 4);
    float* Q       = (float*)carve((size_t)N_ * DIM_ * 4);
    float* cnt     = (float*)carve((size_t)N_ * 4);
    float* e_ws    = (float*)carve((size_t)N_ * 4);
    float* q_star  = (float*)carve((size_t)B_ * 128 * 4);
    float* hl      = (float*)carve((size_t)B_ * 64 * 4);
    float* cl      = (float*)carve((size_t)B_ * 64 * 4);
    int*   cnt_b   = (int*)carve((size_t)B_ * 4);
    int*   off_b   = (int*)carve((size_t)(B_ + 1) * 4);
    float* h1      = (float*)carve((size_t)E_ * MLP_H_ * 4);
    unsigned short* Bh = (unsigned short*)carve((size_t)PC_ * 64 * 2);
    unsigned short* Bl = (unsigned short*)carve((size_t)PC_ * 64 * 2);
    int*   cnt_src = (int*)carve((size_t)N_ * 4);
    int*   src_off = (int*)carve((size_t)(N_ + 1) * 4);
    int*   cur     = (int*)carve((size_t)N_ * 4);
    int*   eord    = (int*)carve((size_t)E_ * 4);
    size_t used = (size_t)(w - (char*)d_ws);
    float* P = (float*)w;
    size_t avail = ws_size > used ? ws_size - used : 0;
    long long nc = (long long)(avail / ((size_t)PC_ * 4));
    if (nc > N_) nc = N_;
    nc &= ~63LL;
    if (nc < 64) nc = 64;
    int NC = (int)nc;

    // init
    hipMemsetAsync(cnt, 0, (size_t)N_ * 4, stream);
    hipMemsetAsync(cnt_b, 0, (size_t)B_ * 4, stream);
    hipMemsetAsync(cnt_src, 0, (size_t)N_ * 4, stream);
    hipMemsetAsync(cur, 0, (size_t)N_ * 4, stream);
    hipMemsetAsync(q_star, 0, (size_t)B_ * 128 * 4, stream);
    hipMemsetAsync(hl, 0, (size_t)B_ * 64 * 4, stream);
    hipMemsetAsync(cl, 0, (size_t)B_ * 64 * 4, stream);

    lin0_kernel<<<(N_ * DIM_ + 255) / 256, 256, 0, stream>>>(x, lin0_w, lin0_b, out_buf);
    mlp1_kernel<<<(E_ * MLP_H_ + 255) / 256, 256, 0, stream>>>(ea, mlp_w1, mlp_b1, h1);
    cnt_kernel<<<(E_ + 255) / 256, 256, 0, stream>>>(dst, cnt);
    count_batch<<<(N_ + 255) / 256, 256, 0, stream>>>(batch, cnt_b);
    scan_off<<<1, 64, 0, stream>>>(cnt_b, off_b);
    hist_src<<<(E_ + 255) / 256, 256, 0, stream>>>(src, cnt_src);
    scan_src<<<1, 256, 0, stream>>>(cnt_src, src_off);
    scatter_src<<<(E_ + 255) / 256, 256, 0, stream>>>(src, cur, src_off, eord);
    prep_b<<<(PC_ * 64 + 255) / 256, 256, 0, stream>>>(mlp_w2, Bh, Bl);

    for (int step = 0; step < 3; ++step) {
        q_kernel<<<(N_ + 3) / 4, 256, 0, stream>>>(out_buf, mlp_b2, Q);
        hipMemsetAsync(agg, 0, (size_t)N_ * DIM_ * 4, stream);
        for (int n0 = 0; n0 < N_; n0 += NC) {
            int n1 = n0 + NC < N_ ? n0 + NC : N_;
            dim3 g(PC_ / 128, (n1 - n0 + 127) / 128);
            p_gemm_mfma<<<g, 256, 0, stream>>>(out_buf, Bh, Bl, P, n0, n1);
            edge_msg<<<(E_ + 3) / 4, 256, 0, stream>>>(P, h1, Q, eord, src, dst,
                                                       src_off, agg, n0, n1);
        }
        gru_kernel<<<(N_ + 3) / 4, 256, 0, stream>>>(out_buf, agg, cnt, conv_root, conv_bias,
                                                     gru_wi, gru_wh, gru_bi, gru_bh);
    }

    for (int s = 0; s < 3; ++s) {
        lstm_kernel<<<B_, 256, 0, stream>>>(q_star, hl, cl, lstm_wi, lstm_wh, lstm_bi, lstm_bh);
        attn_kernel<<<B_, 256, 0, stream>>>(out_buf, off_b, hl, q_star, e_ws);
    }
    head_kernel<<<B_, 64, 0, stream>>>(q_star, lin1_w, lin1_b, lin2_w, lin2_b, y);
}